// Round 4
// baseline (519.847 us; speedup 1.0000x reference)
//
#include <hip/hip_runtime.h>
#include <hip/hip_fp8.h>

typedef unsigned short u16;
typedef unsigned char u8;
typedef unsigned int u32;
typedef short bf16x8 __attribute__((ext_vector_type(8)));
typedef float f32x4 __attribute__((ext_vector_type(4)));
typedef u16 u16x4 __attribute__((ext_vector_type(4)));
typedef int i32x8 __attribute__((ext_vector_type(8)));
typedef long l64x4 __attribute__((ext_vector_type(4)));

#define SCALE_Q 0.044194173824159216f   // 1/sqrt(512)

__device__ __forceinline__ u16 f2b(float f){   // fp32 -> bf16 RNE
  unsigned u = __float_as_uint(f);
  u += 0x7fffu + ((u >> 16) & 1u);
  return (u16)(u >> 16);
}

__device__ __forceinline__ u8 f2e4(float f){   // fp32 -> fp8 e4m3 (OCP)
  return __hip_fp8_e4m3(f).__x;
}

__device__ __forceinline__ void gload16(const void* g, void* l){
  __builtin_amdgcn_global_load_lds(
      (const __attribute__((address_space(1))) void*)g,
      (__attribute__((address_space(3))) void*)l, 16, 0, 0);
}

// ---------------- GroupNorm stats: one block per (b, group) ----------------
__global__ __launch_bounds__(256) void gn_stats(const float* __restrict__ x,
                                                float* __restrict__ stats){
  int bg = blockIdx.x;
  const float4* p4 = (const float4*)(x + (size_t)bg * 65536);
  float s = 0.f, ss = 0.f;
  for (int i = threadIdx.x; i < 16384; i += 256){
    float4 v = p4[i];
    s  += v.x + v.y + v.z + v.w;
    ss += v.x*v.x + v.y*v.y + v.z*v.z + v.w*v.w;
  }
  for (int off = 32; off; off >>= 1){
    s  += __shfl_down(s, off);
    ss += __shfl_down(ss, off);
  }
  __shared__ float as_[4], bs_[4];
  int wid = threadIdx.x >> 6, lid = threadIdx.x & 63;
  if (lid == 0){ as_[wid] = s; bs_[wid] = ss; }
  __syncthreads();
  if (threadIdx.x == 0){
    float S = as_[0]+as_[1]+as_[2]+as_[3], SS = bs_[0]+bs_[1]+bs_[2]+bs_[3];
    float mean = S * (1.f/65536.f);
    float var  = SS * (1.f/65536.f) - mean*mean;
    stats[2*bg]   = mean;
    stats[2*bg+1] = rsqrtf(var + 1e-6f);
  }
}

// ------- normalize + affine + transpose [b,c,N] -> t[b,N,c] (bf16) ---------
__global__ __launch_bounds__(256) void gn_apply_T(const float* __restrict__ x,
                                                  const float* __restrict__ stats,
                                                  const float* __restrict__ gamma,
                                                  const float* __restrict__ beta,
                                                  u16* __restrict__ t){
  __shared__ float tile[32][33];
  int nb = blockIdx.x, cb = blockIdx.y, b = blockIdx.z;
  int tx = threadIdx.x & 31, ty = threadIdx.x >> 5;
  int n0 = nb * 32, c0 = cb * 32;
  #pragma unroll
  for (int i = 0; i < 4; i++){
    int ch = c0 + ty + i*8;
    float mean = stats[2*((b<<5) + (ch>>4))];
    float rstd = stats[2*((b<<5) + (ch>>4)) + 1];
    float v = x[(((size_t)b*512 + ch) << 12) + n0 + tx];
    tile[ty + i*8][tx] = (v - mean) * rstd * gamma[ch] + beta[ch];
  }
  __syncthreads();
  #pragma unroll
  for (int i = 0; i < 4; i++){
    int n = n0 + ty + i*8;
    int ch = c0 + tx;
    t[((size_t)((b<<12) + n))*512 + ch] = f2b(tile[tx][ty + i*8]);
  }
}

// ---------------- fp32 -> bf16 weight conversion (4 matrices) --------------
__global__ __launch_bounds__(256) void w2bf(const float* __restrict__ a,
                                            const float* __restrict__ b,
                                            const float* __restrict__ c,
                                            const float* __restrict__ d,
                                            u16* __restrict__ o){
  int idx = blockIdx.x * 256 + threadIdx.x;
  int which = idx >> 16;
  const float4* src = (const float4*)(which == 0 ? a : which == 1 ? b : which == 2 ? c : d);
  float4 v = src[idx & 65535];
  u16x4 pk;
  pk.x = f2b(v.x); pk.y = f2b(v.y); pk.z = f2b(v.z); pk.w = f2b(v.w);
  *(u16x4*)(o + (size_t)idx*4) = pk;
}

// ------------- fused QKV gemm: grid (128, 12); y>>2 selects matrix ---------
__global__ __launch_bounds__(256, 2) void qkv_gemm(const u16* __restrict__ A,
                                                   const u16* __restrict__ Wcat,
                                                   const float* __restrict__ qbias,
                                                   const float* __restrict__ kbias,
                                                   const float* __restrict__ vbias,
                                                   u8* __restrict__ qo,
                                                   u8* __restrict__ ko,
                                                   u8* __restrict__ vo){
  __shared__ __align__(16) u16 SMEM[8192];     // As | Bs, reused as 16KB stage
  u16* As = SMEM;
  u16* Bs = SMEM + 4096;
  const int t = threadIdx.x;
  const int w = t >> 6, ln = t & 63;
  const int wr = w >> 1, wc = w & 1;
  const int q4 = ln >> 4, l15 = ln & 15;
  const int y = blockIdx.y;
  const int mat = y >> 2, yb = y & 3;
  const int row0 = blockIdx.x * 128;
  const u16* Ab = A    + (size_t)row0 * 512;
  const u16* Bb = Wcat + (size_t)y * 128 * 512;
  f32x4 acc[4][4];
  #pragma unroll
  for (int i = 0; i < 4; i++)
    #pragma unroll
    for (int j = 0; j < 4; j++){
      acc[i][j][0]=0.f; acc[i][j][1]=0.f; acc[i][j][2]=0.f; acc[i][j][3]=0.f;
    }
  for (int kt = 0; kt < 16; ++kt){
    #pragma unroll
    for (int i = 0; i < 2; i++){
      int idx = i*256 + t;
      gload16(Ab + (size_t)(idx>>2)*512 + kt*32 + (idx&3)*8, As + (size_t)idx*8);
      gload16(Bb + (size_t)(idx>>2)*512 + kt*32 + (idx&3)*8, Bs + (size_t)idx*8);
    }
    __syncthreads();
    bf16x8 af[4], bf[4];
    #pragma unroll
    for (int mt = 0; mt < 4; mt++)
      af[mt] = *(const bf16x8*)(As + (wr*64 + mt*16 + l15)*32 + q4*8);
    #pragma unroll
    for (int nt = 0; nt < 4; nt++)
      bf[nt] = *(const bf16x8*)(Bs + (wc*64 + nt*16 + l15)*32 + q4*8);
    #pragma unroll
    for (int mt = 0; mt < 4; mt++)
      #pragma unroll
      for (int nt = 0; nt < 4; nt++)
        acc[mt][nt] = __builtin_amdgcn_mfma_f32_16x16x32_bf16(af[mt], bf[nt], acc[mt][nt], 0, 0, 0);
    __syncthreads();
  }
  const int bb = row0 >> 12;            // batch
  const int tile0 = (row0 >> 6) & 63;   // first 64-token tile of this block
  const int col0 = yb*128 + wc*64;      // global channel base for this wave
  u8* Ls = (u8*)SMEM;                   // 16KB staging

  if (mat == 0){
    #pragma unroll
    for (int nt = 0; nt < 4; nt++){
      int n = col0 + nt*16 + l15;
      float bv = qbias[n];
      #pragma unroll
      for (int mt = 0; mt < 4; mt++){
        int m0 = row0 + wr*64 + mt*16 + q4*4;
        #pragma unroll
        for (int r = 0; r < 4; r++)
          qo[(size_t)(m0 + r)*512 + n] = f2e4(acc[mt][nt][r] + bv);
      }
    }
  } else if (mat == 1){
    // stage into LDS in exact global within-tile layout
    #pragma unroll
    for (int nt = 0; nt < 4; nt++){
      int n = col0 + nt*16 + l15;
      float bv = kbias[n];
      int ksl = wc*2 + (nt >> 1);            // block-local ks (0..3)
      int c3  = ((nt & 1)*2 + (l15 >> 3));   // ch>>3 within 32-ch group
      #pragma unroll
      for (int mt = 0; mt < 4; mt++){
        #pragma unroll
        for (int r = 0; r < 4; r++){
          int kr = mt*16 + q4*4 + r;
          int chunk = c3 ^ ((kr >> 2) & 3);
          Ls[(wr*4 + ksl)*2048 + kr*32 + chunk*8 + (l15 & 7)] = f2e4(acc[mt][nt][r] + bv);
        }
      }
    }
    __syncthreads();
    #pragma unroll
    for (int i = 0; i < 4; i++){
      int ci = i*256 + t;                    // 16B chunk 0..1023
      int ri = ci >> 7, t2 = ri >> 2, ksl2 = ri & 3;
      u8* dst = ko + ((size_t)(bb*64 + tile0 + t2))*32768
                   + (size_t)(yb*4 + ksl2)*2048 + (size_t)(ci & 127)*16;
      *(float4*)dst = *(const float4*)(Ls + (size_t)ci*16);
    }
  } else {
    #pragma unroll
    for (int nt = 0; nt < 4; nt++){
      int n = col0 + nt*16 + l15;
      float bv = vbias[n];
      int nl = n & 127;
      #pragma unroll
      for (int mt = 0; mt < 4; mt++){
        int kv = mt*16 + q4*4;
        u32 pk = (u32)f2e4(acc[mt][nt][0] + bv)
               | ((u32)f2e4(acc[mt][nt][1] + bv) << 8)
               | ((u32)f2e4(acc[mt][nt][2] + bv) << 16)
               | ((u32)f2e4(acc[mt][nt][3] + bv) << 24);
        int phys = (kv >> 3) ^ (n & 7);
        *(u32*)(Ls + wr*8192 + nl*64 + phys*8 + (kv & 4)) = pk;
      }
    }
    __syncthreads();
    #pragma unroll
    for (int i = 0; i < 4; i++){
      int ci = i*256 + t;                    // 16B chunk 0..1023
      int t2 = ci >> 9;
      u8* dst = vo + ((size_t)(bb*64 + tile0 + t2))*32768
                   + (size_t)yb*8192 + (size_t)(ci & 511)*16;
      *(float4*)dst = *(const float4*)(Ls + (size_t)ci*16);
    }
  }
}

// ----------- out-proj gemm + bias + residual + transpose (fp32 out) --------
__global__ __launch_bounds__(256, 2) void out_gemm(const u16* __restrict__ A,
                                                   const u16* __restrict__ Bw,
                                                   const float* __restrict__ bias,
                                                   float* __restrict__ out,
                                                   const float* __restrict__ resid){
  __shared__ __align__(16) u16 As[128*32];
  __shared__ __align__(16) u16 Bs[128*32];
  const int t = threadIdx.x;
  const int w = t >> 6, ln = t & 63;
  const int wr = w >> 1, wc = w & 1;
  const int q4 = ln >> 4, l15 = ln & 15;
  const u16* Ab = A  + (size_t)blockIdx.x * 128 * 512;
  const u16* Bb = Bw + (size_t)blockIdx.y * 128 * 512;
  f32x4 acc[4][4];
  #pragma unroll
  for (int i = 0; i < 4; i++)
    #pragma unroll
    for (int j = 0; j < 4; j++){
      acc[i][j][0]=0.f; acc[i][j][1]=0.f; acc[i][j][2]=0.f; acc[i][j][3]=0.f;
    }
  for (int kt = 0; kt < 16; ++kt){
    #pragma unroll
    for (int i = 0; i < 2; i++){
      int idx = i*256 + t;
      gload16(Ab + (size_t)(idx>>2)*512 + kt*32 + (idx&3)*8, As + (size_t)idx*8);
      gload16(Bb + (size_t)(idx>>2)*512 + kt*32 + (idx&3)*8, Bs + (size_t)idx*8);
    }
    __syncthreads();
    bf16x8 af[4], bf[4];
    #pragma unroll
    for (int mt = 0; mt < 4; mt++)
      af[mt] = *(const bf16x8*)(As + (wr*64 + mt*16 + l15)*32 + q4*8);
    #pragma unroll
    for (int nt = 0; nt < 4; nt++)
      bf[nt] = *(const bf16x8*)(Bs + (wc*64 + nt*16 + l15)*32 + q4*8);
    #pragma unroll
    for (int mt = 0; mt < 4; mt++)
      #pragma unroll
      for (int nt = 0; nt < 4; nt++)
        acc[mt][nt] = __builtin_amdgcn_mfma_f32_16x16x32_bf16(af[mt], bf[nt], acc[mt][nt], 0, 0, 0);
    __syncthreads();
  }
  const int row0 = blockIdx.x*128 + wr*64;
  const int col0 = blockIdx.y*128 + wc*64;
  #pragma unroll
  for (int nt = 0; nt < 4; nt++){
    int n = col0 + nt*16 + l15;
    float bv = bias[n];
    #pragma unroll
    for (int mt = 0; mt < 4; mt++){
      int m0 = row0 + mt*16 + q4*4;
      int bb = m0 >> 12, tok = m0 & 4095;
      size_t base = (((size_t)(bb*512 + n)) << 12) + tok;
      float4 xr = *(const float4*)(resid + base);
      float4 ov;
      ov.x = acc[mt][nt][0] + bv + xr.x;
      ov.y = acc[mt][nt][1] + bv + xr.y;
      ov.z = acc[mt][nt][2] + bv + xr.z;
      ov.w = acc[mt][nt][3] + bv + xr.w;
      *(float4*)(out + base) = ov;
    }
  }
}

// ---------------------------- flash attention ------------------------------
// 512 threads (8 waves), 2 blocks/CU. PV lags S by one tile; one barrier/iter.
// S via MX-scaled mfma_scale_f32_16x16x128 (unit e8m0 scales == plain fp8 at
// 2x rate): 4 MFMAs/wave instead of 16. S computed SWAPPED (A=K, B=Q) so each
// lane holds 4 consecutive kv of one q-row -> packed u32 P-write, cvt_pk fp8,
// scalar l-row with 2-shuffle reduction. P values/layout in LDS unchanged;
// PV path (16x16x32 fp8) and epilogue untouched.
__global__ __launch_bounds__(512, 4) void attn_fwd(const u8* __restrict__ q,
                                                   const u8* __restrict__ kt,
                                                   const u8* __restrict__ vt,
                                                   u16* __restrict__ outO){
  __shared__ __align__(16) u8 Kb[2][32768];    // 2 x 32KB fp8 K tiles
  __shared__ __align__(16) u8 Pb[2][32*72];    // P fp8 dbuf [qrow32][kv64 +8]
  __shared__ __align__(16) float lL[128];      // [kvq4][row32]

  const int t = threadIdx.x, w = t >> 6, ln = t & 63;
  const int q4 = ln >> 4, l15 = ln & 15;
  const int rt = w >> 2, kvq = w & 3;          // S role: row-tile, kv quarter
  const int b = blockIdx.y, q0 = blockIdx.x * 32;
  const u8* kbase = kt + ((size_t)b << 21);
  const u8* vbase = vt + ((size_t)b << 21);

  // Q fragments for MX K=128: lane holds Q[row][kk*128 + q4*32 .. +32]
  i32x8 qm[4];
  {
    const u8* qr = q + (size_t)((b<<12) + q0 + rt*16 + l15) * 512;
    #pragma unroll
    for (int kk = 0; kk < 4; kk++)
      qm[kk] = *(const i32x8*)(qr + kk*128 + q4*32);
  }
  f32x4 oacc[2][4];
  #pragma unroll
  for (int i = 0; i < 2; i++)
    #pragma unroll
    for (int j = 0; j < 4; j++){
      oacc[i][j][0]=0.f; oacc[i][j][1]=0.f; oacc[i][j][2]=0.f; oacc[i][j][3]=0.f;
    }
  float lrow = 0.f;

  // K fragment offsets: lane reads full 32-ch group of ks = kk*4+q4, row kr,
  // 4x 8B chunks with the store-side XOR swizzle undone.
  const int kr = kvq*16 + l15;
  const int sw = (kr >> 2) & 3;
  const int kof0 = q4*2048 + kr*32 + (((0 ^ sw)) << 3);
  const int kof1 = q4*2048 + kr*32 + (((1 ^ sw)) << 3);
  const int kof2 = q4*2048 + kr*32 + (((2 ^ sw)) << 3);
  const int kof3 = q4*2048 + kr*32 + (((3 ^ sw)) << 3);

  // prologue: DMA K tile 0 into Kb[0] (2048 x 16B chunks, 4 per thread)
  #pragma unroll
  for (int i = 0; i < 4; i++){
    int ci = i*512 + t;
    gload16(kbase + (size_t)ci*16, &Kb[0][ci*16]);
  }
  __syncthreads();

  #pragma unroll 1
  for (int j = 0; j < 64; ++j){
    // 1. DMA K tile j+1 into other buffer (full-iter latency cover)
    if (j < 63){
      const u8* kn = kbase + ((size_t)(j + 1) << 15);
      u8* kd = Kb[(j + 1) & 1];
      #pragma unroll
      for (int i = 0; i < 4; i++){
        int ci = i*512 + t;
        gload16(kn + (size_t)ci*16, kd + ci*16);
      }
    }
    // 2. V(j-1) + P(j-1) fragment loads (consumed by PV this iter;
    //    latency hidden under S(j)'s MFMA cluster)
    long vf0[4], vf1[4];
    long pf00, pf01, pf10, pf11;
    if (j > 0){
      const u8* vtile = vbase + ((size_t)(j - 1) << 15);
      #pragma unroll
      for (int ct = 0; ct < 4; ct++){
        int ch = 64*w + ct*16 + l15;
        int swz = ch & 7;
        const u8* vr = vtile + (size_t)ch*64;
        vf0[ct] = *(const long*)(vr + ((q4 ^ swz) << 3));
        vf1[ct] = *(const long*)(vr + (((4 + q4) ^ swz) << 3));
      }
      const u8* Pp = Pb[(j - 1) & 1];
      pf00 = *(const long*)(Pp + l15*72 + q4*8);
      pf01 = *(const long*)(Pp + l15*72 + 32 + q4*8);
      pf10 = *(const long*)(Pp + (16 + l15)*72 + q4*8);
      pf11 = *(const long*)(Pp + (16 + l15)*72 + 32 + q4*8);
    }
    // 3. S^T(j) = K Q^T via MX-scaled K=128 fp8 (unit scales): 4 MFMAs,
    //    2 chains. Output: col=l15=q, row=q4*4+r = kv within 16-tile.
    const u8* Kp = Kb[j & 1];
    f32x4 sA0, sA1;
    sA0[0]=0.f;sA0[1]=0.f;sA0[2]=0.f;sA0[3]=0.f;
    sA1[0]=0.f;sA1[1]=0.f;sA1[2]=0.f;sA1[3]=0.f;
    __builtin_amdgcn_s_setprio(1);
    #pragma unroll
    for (int kk = 0; kk < 4; kk++){
      const u8* e = Kp + kk*8192;
      l64x4 kl;
      kl[0] = *(const long*)(e + kof0);
      kl[1] = *(const long*)(e + kof1);
      kl[2] = *(const long*)(e + kof2);
      kl[3] = *(const long*)(e + kof3);
      i32x8 kb = __builtin_bit_cast(i32x8, kl);
      if (kk & 1)
        sA1 = __builtin_amdgcn_mfma_scale_f32_16x16x128_f8f6f4(
                  kb, qm[kk], sA1, 0, 0, 0, 0x7F, 0, 0x7F);
      else
        sA0 = __builtin_amdgcn_mfma_scale_f32_16x16x128_f8f6f4(
                  kb, qm[kk], sA0, 0, 0, 0, 0x7F, 0, 0x7F);
    }
    // 4. PV(j-1): independent of S(j); P/V fragments loaded in step 2
    if (j > 0){
      #pragma unroll
      for (int ct = 0; ct < 4; ct++){
        f32x4 a0 = oacc[0][ct], a1 = oacc[1][ct];
        a0 = __builtin_amdgcn_mfma_f32_16x16x32_fp8_fp8(pf00, vf0[ct], a0, 0, 0, 0);
        a1 = __builtin_amdgcn_mfma_f32_16x16x32_fp8_fp8(pf10, vf0[ct], a1, 0, 0, 0);
        a0 = __builtin_amdgcn_mfma_f32_16x16x32_fp8_fp8(pf01, vf1[ct], a0, 0, 0, 0);
        a1 = __builtin_amdgcn_mfma_f32_16x16x32_fp8_fp8(pf11, vf1[ct], a1, 0, 0, 0);
        oacc[0][ct] = a0; oacc[1][ct] = a1;
      }
    }
    __builtin_amdgcn_s_setprio(0);
    // 5. softmax(j): lane owns q-row rt*16+l15, kv = kvq*16 + q4*4 + 0..3
    {
      float e0 = __expf((sA0[0] + sA1[0]) * SCALE_Q);
      float e1 = __expf((sA0[1] + sA1[1]) * SCALE_Q);
      float e2 = __expf((sA0[2] + sA1[2]) * SCALE_Q);
      float e3 = __expf((sA0[3] + sA1[3]) * SCALE_Q);
      lrow += (e0 + e1) + (e2 + e3);
#if defined(__has_builtin) && __has_builtin(__builtin_amdgcn_cvt_pk_fp8_f32)
      int pk = __builtin_amdgcn_cvt_pk_fp8_f32(e0, e1, 0, false);
      pk = __builtin_amdgcn_cvt_pk_fp8_f32(e2, e3, pk, true);
#else
      u32 pk = (u32)f2e4(e0) | ((u32)f2e4(e1) << 8)
             | ((u32)f2e4(e2) << 16) | ((u32)f2e4(e3) << 24);
#endif
      *(u32*)(Pb[j & 1] + (rt*16 + l15)*72 + kvq*16 + q4*4) = pk;
    }
    // 6. one barrier: P(j) visible; K(j+1) DMA + V loads drained
    __syncthreads();
  }

  // ---- epilogue: final PV(63) -- P(63) in Pb[1], V(63) loaded fresh ----
  {
    const u8* vtile = vbase + ((size_t)63 << 15);
    long vf0[4], vf1[4];
    #pragma unroll
    for (int ct = 0; ct < 4; ct++){
      int ch = 64*w + ct*16 + l15;
      int swz = ch & 7;
      const u8* vr = vtile + (size_t)ch*64;
      vf0[ct] = *(const long*)(vr + ((q4 ^ swz) << 3));
      vf1[ct] = *(const long*)(vr + (((4 + q4) ^ swz) << 3));
    }
    const u8* Pp = Pb[1];
    long pf00 = *(const long*)(Pp + l15*72 + q4*8);
    long pf01 = *(const long*)(Pp + l15*72 + 32 + q4*8);
    long pf10 = *(const long*)(Pp + (16 + l15)*72 + q4*8);
    long pf11 = *(const long*)(Pp + (16 + l15)*72 + 32 + q4*8);
    #pragma unroll
    for (int ct = 0; ct < 4; ct++){
      f32x4 a0 = oacc[0][ct], a1 = oacc[1][ct];
      a0 = __builtin_amdgcn_mfma_f32_16x16x32_fp8_fp8(pf00, vf0[ct], a0, 0, 0, 0);
      a1 = __builtin_amdgcn_mfma_f32_16x16x32_fp8_fp8(pf10, vf0[ct], a1, 0, 0, 0);
      a0 = __builtin_amdgcn_mfma_f32_16x16x32_fp8_fp8(pf01, vf1[ct], a0, 0, 0, 0);
      a1 = __builtin_amdgcn_mfma_f32_16x16x32_fp8_fp8(pf11, vf1[ct], a1, 0, 0, 0);
      oacc[0][ct] = a0; oacc[1][ct] = a1;
    }
  }

  // ---- epilogue: reduce l across q4 groups + the four kv-quarter waves ----
  {
    float v = lrow;
    v += __shfl_xor(v, 16);
    v += __shfl_xor(v, 32);
    if (ln < 16) lL[kvq*32 + rt*16 + l15] = v;
  }
  __syncthreads();
  #pragma unroll
  for (int rr = 0; rr < 2; rr++){
    #pragma unroll
    for (int r = 0; r < 4; r++){
      int row = rr*16 + q4*4 + r;
      float inv = 1.f / (lL[row] + lL[32 + row] + lL[64 + row] + lL[96 + row]);
      u16* op = outO + ((size_t)b << 21) + (size_t)(q0 + row)*512 + 64*w + l15;
      #pragma unroll
      for (int ct = 0; ct < 4; ct++)
        op[ct*16] = f2b(oacc[rr][ct][r] * inv);
    }
  }
}

extern "C" void kernel_launch(void* const* d_in, const int* in_sizes, int n_in,
                              void* d_out, int out_size, void* d_ws, size_t ws_size,
                              hipStream_t stream){
  const float* x     = (const float*)d_in[0];
  const float* gamma = (const float*)d_in[1];
  const float* beta  = (const float*)d_in[2];
  const float* wq_w  = (const float*)d_in[3];
  const float* wq_b  = (const float*)d_in[4];
  const float* wk_w  = (const float*)d_in[5];
  const float* wk_b  = (const float*)d_in[6];
  const float* wv_w  = (const float*)d_in[7];
  const float* wv_b  = (const float*)d_in[8];
  const float* out_w = (const float*)d_in[9];
  const float* out_b = (const float*)d_in[10];

  char* ws = (char*)d_ws;
  float* stats = (float*)ws;                                   // 1 KB
  u16* tbuf = (u16*)(ws + 4096);                               // 16 MB (t, then O)
  size_t off = 4096 + (size_t)16*1024*1024;
  u16* Wcat = (u16*)(ws + off); off += (size_t)4*512*512*2;    // 2 MB
  u8*  qb   = (u8*)(ws + off);  off += (size_t)16*1024*1024;   // Q fp8
  u8*  ktb  = (u8*)(ws + off);  off += (size_t)16*1024*1024;   // K fp8 tiled
  u8*  vtb  = (u8*)(ws + off);  off += (size_t)16*1024*1024;   // V fp8 tiled

  gn_stats<<<128, 256, 0, stream>>>(x, stats);
  gn_apply_T<<<dim3(128, 16, 4), 256, 0, stream>>>(x, stats, gamma, beta, tbuf);
  w2bf<<<1024, 256, 0, stream>>>(wq_w, wk_w, wv_w, out_w, Wcat);
  u16* Wo = Wcat + 3*512*512;
  qkv_gemm<<<dim3(128, 12), 256, 0, stream>>>(tbuf, Wcat, wq_b, wk_b, wv_b,
                                              qb, ktb, vtb);
  attn_fwd<<<dim3(128, 4), 512, 0, stream>>>(qb, ktb, vtb, tbuf);
  out_gemm<<<dim3(128, 4), 256, 0, stream>>>(tbuf, Wo, out_b, (float*)d_out, x);
}

// Round 5
// 378.963 us; speedup vs baseline: 1.3718x; 1.3718x over previous
//
#include <hip/hip_runtime.h>
#include <hip/hip_fp8.h>

typedef unsigned short u16;
typedef unsigned char u8;
typedef unsigned int u32;
typedef short bf16x8 __attribute__((ext_vector_type(8)));
typedef float f32x4 __attribute__((ext_vector_type(4)));
typedef u16 u16x4 __attribute__((ext_vector_type(4)));

#define SCALE_Q 0.044194173824159216f   // 1/sqrt(512)

__device__ __forceinline__ u16 f2b(float f){   // fp32 -> bf16 RNE
  unsigned u = __float_as_uint(f);
  u += 0x7fffu + ((u >> 16) & 1u);
  return (u16)(u >> 16);
}

__device__ __forceinline__ u8 f2e4(float f){   // fp32 -> fp8 e4m3 (OCP)
  return __hip_fp8_e4m3(f).__x;
}

__device__ __forceinline__ u32 pk4e4(float e0, float e1, float e2, float e3){
#if defined(__has_builtin) && __has_builtin(__builtin_amdgcn_cvt_pk_fp8_f32)
  int pk = __builtin_amdgcn_cvt_pk_fp8_f32(e0, e1, 0, false);
  pk = __builtin_amdgcn_cvt_pk_fp8_f32(e2, e3, pk, true);
  return (u32)pk;
#else
  return (u32)f2e4(e0) | ((u32)f2e4(e1) << 8)
       | ((u32)f2e4(e2) << 16) | ((u32)f2e4(e3) << 24);
#endif
}

__device__ __forceinline__ void gload16(const void* g, void* l){
  __builtin_amdgcn_global_load_lds(
      (const __attribute__((address_space(1))) void*)g,
      (__attribute__((address_space(3))) void*)l, 16, 0, 0);
}

// ---------------- GroupNorm stats: one block per (b, group) ----------------
__global__ __launch_bounds__(256) void gn_stats(const float* __restrict__ x,
                                                float* __restrict__ stats){
  int bg = blockIdx.x;
  const float4* p4 = (const float4*)(x + (size_t)bg * 65536);
  float s = 0.f, ss = 0.f;
  for (int i = threadIdx.x; i < 16384; i += 256){
    float4 v = p4[i];
    s  += v.x + v.y + v.z + v.w;
    ss += v.x*v.x + v.y*v.y + v.z*v.z + v.w*v.w;
  }
  for (int off = 32; off; off >>= 1){
    s  += __shfl_down(s, off);
    ss += __shfl_down(ss, off);
  }
  __shared__ float as_[4], bs_[4];
  int wid = threadIdx.x >> 6, lid = threadIdx.x & 63;
  if (lid == 0){ as_[wid] = s; bs_[wid] = ss; }
  __syncthreads();
  if (threadIdx.x == 0){
    float S = as_[0]+as_[1]+as_[2]+as_[3], SS = bs_[0]+bs_[1]+bs_[2]+bs_[3];
    float mean = S * (1.f/65536.f);
    float var  = SS * (1.f/65536.f) - mean*mean;
    stats[2*bg]   = mean;
    stats[2*bg+1] = rsqrtf(var + 1e-6f);
  }
}

// ------- normalize + affine + transpose [b,c,N] -> t[b,N,c] (bf16) ---------
__global__ __launch_bounds__(256) void gn_apply_T(const float* __restrict__ x,
                                                  const float* __restrict__ stats,
                                                  const float* __restrict__ gamma,
                                                  const float* __restrict__ beta,
                                                  u16* __restrict__ t){
  __shared__ float tile[32][33];
  int nb = blockIdx.x, cb = blockIdx.y, b = blockIdx.z;
  int tx = threadIdx.x & 31, ty = threadIdx.x >> 5;
  int n0 = nb * 32, c0 = cb * 32;
  #pragma unroll
  for (int i = 0; i < 4; i++){
    int ch = c0 + ty + i*8;
    float mean = stats[2*((b<<5) + (ch>>4))];
    float rstd = stats[2*((b<<5) + (ch>>4)) + 1];
    float v = x[(((size_t)b*512 + ch) << 12) + n0 + tx];
    tile[ty + i*8][tx] = (v - mean) * rstd * gamma[ch] + beta[ch];
  }
  __syncthreads();
  #pragma unroll
  for (int i = 0; i < 4; i++){
    int n = n0 + ty + i*8;
    int ch = c0 + tx;
    t[((size_t)((b<<12) + n))*512 + ch] = f2b(tile[tx][ty + i*8]);
  }
}

// ---------------- fp32 -> bf16 weight conversion (4 matrices) --------------
__global__ __launch_bounds__(256) void w2bf(const float* __restrict__ a,
                                            const float* __restrict__ b,
                                            const float* __restrict__ c,
                                            const float* __restrict__ d,
                                            u16* __restrict__ o){
  int idx = blockIdx.x * 256 + threadIdx.x;
  int which = idx >> 16;
  const float4* src = (const float4*)(which == 0 ? a : which == 1 ? b : which == 2 ? c : d);
  float4 v = src[idx & 65535];
  u16x4 pk;
  pk.x = f2b(v.x); pk.y = f2b(v.y); pk.z = f2b(v.z); pk.w = f2b(v.w);
  *(u16x4*)(o + (size_t)idx*4) = pk;
}

// ------------- fused QKV gemm: grid (128, 12); y>>2 selects matrix ---------
__global__ __launch_bounds__(256, 2) void qkv_gemm(const u16* __restrict__ A,
                                                   const u16* __restrict__ Wcat,
                                                   const float* __restrict__ qbias,
                                                   const float* __restrict__ kbias,
                                                   const float* __restrict__ vbias,
                                                   u8* __restrict__ qo,
                                                   u8* __restrict__ ko,
                                                   u8* __restrict__ vo){
  __shared__ __align__(16) u16 SMEM[8192];     // As | Bs, reused as 16KB stage
  u16* As = SMEM;
  u16* Bs = SMEM + 4096;
  const int t = threadIdx.x;
  const int w = t >> 6, ln = t & 63;
  const int wr = w >> 1, wc = w & 1;
  const int q4 = ln >> 4, l15 = ln & 15;
  const int y = blockIdx.y;
  const int mat = y >> 2, yb = y & 3;
  const int row0 = blockIdx.x * 128;
  const u16* Ab = A    + (size_t)row0 * 512;
  const u16* Bb = Wcat + (size_t)y * 128 * 512;
  f32x4 acc[4][4];
  #pragma unroll
  for (int i = 0; i < 4; i++)
    #pragma unroll
    for (int j = 0; j < 4; j++){
      acc[i][j][0]=0.f; acc[i][j][1]=0.f; acc[i][j][2]=0.f; acc[i][j][3]=0.f;
    }
  for (int kt = 0; kt < 16; ++kt){
    #pragma unroll
    for (int i = 0; i < 2; i++){
      int idx = i*256 + t;
      gload16(Ab + (size_t)(idx>>2)*512 + kt*32 + (idx&3)*8, As + (size_t)idx*8);
      gload16(Bb + (size_t)(idx>>2)*512 + kt*32 + (idx&3)*8, Bs + (size_t)idx*8);
    }
    __syncthreads();
    bf16x8 af[4], bf[4];
    #pragma unroll
    for (int mt = 0; mt < 4; mt++)
      af[mt] = *(const bf16x8*)(As + (wr*64 + mt*16 + l15)*32 + q4*8);
    #pragma unroll
    for (int nt = 0; nt < 4; nt++)
      bf[nt] = *(const bf16x8*)(Bs + (wc*64 + nt*16 + l15)*32 + q4*8);
    #pragma unroll
    for (int mt = 0; mt < 4; mt++)
      #pragma unroll
      for (int nt = 0; nt < 4; nt++)
        acc[mt][nt] = __builtin_amdgcn_mfma_f32_16x16x32_bf16(af[mt], bf[nt], acc[mt][nt], 0, 0, 0);
    __syncthreads();
  }
  const int bb = row0 >> 12;            // batch
  const int tile0 = (row0 >> 6) & 63;   // first 64-token tile of this block
  const int col0 = yb*128 + wc*64;      // global channel base for this wave
  u8* Ls = (u8*)SMEM;                   // 16KB staging

  if (mat == 0){
    #pragma unroll
    for (int nt = 0; nt < 4; nt++){
      int n = col0 + nt*16 + l15;
      float bv = qbias[n];
      #pragma unroll
      for (int mt = 0; mt < 4; mt++){
        int m0 = row0 + wr*64 + mt*16 + q4*4;
        #pragma unroll
        for (int r = 0; r < 4; r++)
          qo[(size_t)(m0 + r)*512 + n] = f2e4(acc[mt][nt][r] + bv);
      }
    }
  } else if (mat == 1){
    // stage into LDS in exact global within-tile layout
    #pragma unroll
    for (int nt = 0; nt < 4; nt++){
      int n = col0 + nt*16 + l15;
      float bv = kbias[n];
      int ksl = wc*2 + (nt >> 1);            // block-local ks (0..3)
      int c3  = ((nt & 1)*2 + (l15 >> 3));   // ch>>3 within 32-ch group
      #pragma unroll
      for (int mt = 0; mt < 4; mt++){
        #pragma unroll
        for (int r = 0; r < 4; r++){
          int kr = mt*16 + q4*4 + r;
          int chunk = c3 ^ ((kr >> 2) & 3);
          Ls[(wr*4 + ksl)*2048 + kr*32 + chunk*8 + (l15 & 7)] = f2e4(acc[mt][nt][r] + bv);
        }
      }
    }
    __syncthreads();
    #pragma unroll
    for (int i = 0; i < 4; i++){
      int ci = i*256 + t;                    // 16B chunk 0..1023
      int ri = ci >> 7, t2 = ri >> 2, ksl2 = ri & 3;
      u8* dst = ko + ((size_t)(bb*64 + tile0 + t2))*32768
                   + (size_t)(yb*4 + ksl2)*2048 + (size_t)(ci & 127)*16;
      *(float4*)dst = *(const float4*)(Ls + (size_t)ci*16);
    }
  } else {
    #pragma unroll
    for (int nt = 0; nt < 4; nt++){
      int n = col0 + nt*16 + l15;
      float bv = vbias[n];
      int nl = n & 127;
      #pragma unroll
      for (int mt = 0; mt < 4; mt++){
        int kv = mt*16 + q4*4;
        u32 pk = (u32)f2e4(acc[mt][nt][0] + bv)
               | ((u32)f2e4(acc[mt][nt][1] + bv) << 8)
               | ((u32)f2e4(acc[mt][nt][2] + bv) << 16)
               | ((u32)f2e4(acc[mt][nt][3] + bv) << 24);
        int phys = (kv >> 3) ^ (n & 7);
        *(u32*)(Ls + wr*8192 + nl*64 + phys*8 + (kv & 4)) = pk;
      }
    }
    __syncthreads();
    #pragma unroll
    for (int i = 0; i < 4; i++){
      int ci = i*256 + t;                    // 16B chunk 0..1023
      int t2 = ci >> 9;
      u8* dst = vo + ((size_t)(bb*64 + tile0 + t2))*32768
                   + (size_t)yb*8192 + (size_t)(ci & 511)*16;
      *(float4*)dst = *(const float4*)(Ls + (size_t)ci*16);
    }
  }
}

// ----------- out-proj gemm + bias + residual + transpose (fp32 out) --------
__global__ __launch_bounds__(256, 2) void out_gemm(const u16* __restrict__ A,
                                                   const u16* __restrict__ Bw,
                                                   const float* __restrict__ bias,
                                                   float* __restrict__ out,
                                                   const float* __restrict__ resid){
  __shared__ __align__(16) u16 As[128*32];
  __shared__ __align__(16) u16 Bs[128*32];
  const int t = threadIdx.x;
  const int w = t >> 6, ln = t & 63;
  const int wr = w >> 1, wc = w & 1;
  const int q4 = ln >> 4, l15 = ln & 15;
  const u16* Ab = A  + (size_t)blockIdx.x * 128 * 512;
  const u16* Bb = Bw + (size_t)blockIdx.y * 128 * 512;
  f32x4 acc[4][4];
  #pragma unroll
  for (int i = 0; i < 4; i++)
    #pragma unroll
    for (int j = 0; j < 4; j++){
      acc[i][j][0]=0.f; acc[i][j][1]=0.f; acc[i][j][2]=0.f; acc[i][j][3]=0.f;
    }
  for (int kt = 0; kt < 16; ++kt){
    #pragma unroll
    for (int i = 0; i < 2; i++){
      int idx = i*256 + t;
      gload16(Ab + (size_t)(idx>>2)*512 + kt*32 + (idx&3)*8, As + (size_t)idx*8);
      gload16(Bb + (size_t)(idx>>2)*512 + kt*32 + (idx&3)*8, Bs + (size_t)idx*8);
    }
    __syncthreads();
    bf16x8 af[4], bf[4];
    #pragma unroll
    for (int mt = 0; mt < 4; mt++)
      af[mt] = *(const bf16x8*)(As + (wr*64 + mt*16 + l15)*32 + q4*8);
    #pragma unroll
    for (int nt = 0; nt < 4; nt++)
      bf[nt] = *(const bf16x8*)(Bs + (wc*64 + nt*16 + l15)*32 + q4*8);
    #pragma unroll
    for (int mt = 0; mt < 4; mt++)
      #pragma unroll
      for (int nt = 0; nt < 4; nt++)
        acc[mt][nt] = __builtin_amdgcn_mfma_f32_16x16x32_bf16(af[mt], bf[nt], acc[mt][nt], 0, 0, 0);
    __syncthreads();
  }
  const int row0 = blockIdx.x*128 + wr*64;
  const int col0 = blockIdx.y*128 + wc*64;
  #pragma unroll
  for (int nt = 0; nt < 4; nt++){
    int n = col0 + nt*16 + l15;
    float bv = bias[n];
    #pragma unroll
    for (int mt = 0; mt < 4; mt++){
      int m0 = row0 + mt*16 + q4*4;
      int bb = m0 >> 12, tok = m0 & 4095;
      size_t base = (((size_t)(bb*512 + n)) << 12) + tok;
      float4 xr = *(const float4*)(resid + base);
      float4 ov;
      ov.x = acc[mt][nt][0] + bv + xr.x;
      ov.y = acc[mt][nt][1] + bv + xr.y;
      ov.z = acc[mt][nt][2] + bv + xr.z;
      ov.w = acc[mt][nt][3] + bv + xr.w;
      *(float4*)(out + base) = ov;
    }
  }
}

// ---------------------------- flash attention ------------------------------
// WAVE-SPECIALIZED producer/consumer. 512 threads, 1 block/CU (140KB LDS,
// 2 waves/SIMD => 256-VGPR budget, no spill). KVBLK=128 (2x 64-kv tiles per
// window, 32 windows, half the barriers).
//   waves 0-3 (S): (rt = w&1: q-row tile, kvH = w>>1: 64-kv half). Swapped
//     S^T = mfma(K, Q): lane (q4,l15) holds 4 consecutive kv of q-row
//     rt*16+l15 -> packed u32 P-write, scalar l-row. 64 MFMA/iter.
//   waves 4-7 (PV): 128-ch strip each; P(window-1) from LDS dbuf, V from L2.
//     64 MFMA/iter.
// One barrier per window. S softmax VALU overlaps PV MFMA on each SIMD.
#define PSTR 140                        // P row stride (<=2-way bank alias)
__global__ __launch_bounds__(512, 2) void attn_fwd(const u8* __restrict__ q,
                                                   const u8* __restrict__ kt,
                                                   const u8* __restrict__ vt,
                                                   u16* __restrict__ outO){
  __shared__ __align__(16) u8 Kb[2][65536];    // 2 x (two 32KB fp8 K tiles)
  __shared__ __align__(16) u8 Pb[2][32*PSTR];  // P fp8 dbuf [qrow32][kv128]
  __shared__ __align__(16) float lL[64];       // [kvH2][row32]

  const int t = threadIdx.x, w = t >> 6, ln = t & 63;
  const int q4 = ln >> 4, l15 = ln & 15;
  const int b = blockIdx.y, q0 = blockIdx.x * 32;
  const u8* kbase = kt + ((size_t)b << 21);
  const u8* vbase = vt + ((size_t)b << 21);
  const bool isS = (w < 4);
  const int rt = w & 1, kvH = w >> 1;          // S roles (valid for w<4)
  const int wp = w & 3, ch0 = wp * 128;        // PV roles (valid for w>=4)

  // ---- S state: Q fragments (rows q0 + rt*16 + l15, full 512 ch) ----
  long qf[16];
  int ko0, ko1, ko2, ko3;
  float lrow = 0.f;
  if (isS){
    const u8* qr = q + (size_t)((b<<12) + q0 + rt*16 + l15) * 512;
    #pragma unroll
    for (int ks = 0; ks < 16; ks++) qf[ks] = *(const long*)(qr + ks*32 + q4*8);
    int kr0 = 0*16 + l15, kr1 = 1*16 + l15, kr2 = 2*16 + l15, kr3 = 3*16 + l15;
    ko0 = kr0*32 + ((q4 ^ ((kr0 >> 2) & 3)) << 3);
    ko1 = kr1*32 + ((q4 ^ ((kr1 >> 2) & 3)) << 3);
    ko2 = kr2*32 + ((q4 ^ ((kr2 >> 2) & 3)) << 3);
    ko3 = kr3*32 + ((q4 ^ ((kr3 >> 2) & 3)) << 3);
  }

  // ---- PV state ----
  f32x4 oacc[2][8];
  int vo0[8], vo1[8];
  if (!isS){
    #pragma unroll
    for (int i = 0; i < 2; i++)
      #pragma unroll
      for (int j = 0; j < 8; j++){
        oacc[i][j][0]=0.f; oacc[i][j][1]=0.f; oacc[i][j][2]=0.f; oacc[i][j][3]=0.f;
      }
    #pragma unroll
    for (int ct = 0; ct < 8; ct++){
      int ch = ch0 + ct*16 + l15;
      int swz = ch & 7;
      vo0[ct] = ch*64 + ((q4 ^ swz) << 3);
      vo1[ct] = ch*64 + (((4 + q4) ^ swz) << 3);
    }
  }

  // prologue: DMA K window 0 (tiles 0,1 = 64KB; 8 chunks/thread)
  #pragma unroll
  for (int i = 0; i < 8; i++){
    int ci = i*512 + t;
    gload16(kbase + (size_t)ci*16, &Kb[0][ci*16]);
  }
  __syncthreads();

  #pragma unroll 1
  for (int j = 0; j < 32; ++j){
    // 1. all waves: DMA K window j+1 into other buffer
    if (j < 31){
      const u8* kn = kbase + ((size_t)(j + 1) << 16);
      u8* kd = Kb[(j + 1) & 1];
      #pragma unroll
      for (int i = 0; i < 8; i++){
        int ci = i*512 + t;
        gload16(kn + (size_t)ci*16, kd + ci*16);
      }
    }
    if (isS){
      // 2a. S(window j): 4 independent 16-deep chains (one per 16-kv tile)
      const u8* Kp = &Kb[j & 1][kvH * 32768];
      f32x4 s0, s1, s2, s3;
      s0[0]=0.f;s0[1]=0.f;s0[2]=0.f;s0[3]=0.f;
      s1[0]=0.f;s1[1]=0.f;s1[2]=0.f;s1[3]=0.f;
      s2[0]=0.f;s2[1]=0.f;s2[2]=0.f;s2[3]=0.f;
      s3[0]=0.f;s3[1]=0.f;s3[2]=0.f;s3[3]=0.f;
      __builtin_amdgcn_s_setprio(1);
      #pragma unroll
      for (int ks = 0; ks < 16; ks++){
        const u8* e = Kp + ks*2048;
        long k0 = *(const long*)(e + ko0);
        long k1 = *(const long*)(e + ko1);
        long k2 = *(const long*)(e + ko2);
        long k3 = *(const long*)(e + ko3);
        long qv = qf[ks];
        s0 = __builtin_amdgcn_mfma_f32_16x16x32_fp8_fp8(k0, qv, s0, 0, 0, 0);
        s1 = __builtin_amdgcn_mfma_f32_16x16x32_fp8_fp8(k1, qv, s1, 0, 0, 0);
        s2 = __builtin_amdgcn_mfma_f32_16x16x32_fp8_fp8(k2, qv, s2, 0, 0, 0);
        s3 = __builtin_amdgcn_mfma_f32_16x16x32_fp8_fp8(k3, qv, s3, 0, 0, 0);
      }
      __builtin_amdgcn_s_setprio(0);
      // 3a. softmax: lane owns q-row rt*16+l15; kv = kvH*64 + t*16 + q4*4+r
      u8* Pw = Pb[j & 1] + (rt*16 + l15)*PSTR + kvH*64 + q4*4;
      {
        float e0 = __expf(s0[0]*SCALE_Q), e1 = __expf(s0[1]*SCALE_Q);
        float e2 = __expf(s0[2]*SCALE_Q), e3 = __expf(s0[3]*SCALE_Q);
        lrow += (e0+e1)+(e2+e3);
        *(u32*)(Pw) = pk4e4(e0, e1, e2, e3);
        e0 = __expf(s1[0]*SCALE_Q); e1 = __expf(s1[1]*SCALE_Q);
        e2 = __expf(s1[2]*SCALE_Q); e3 = __expf(s1[3]*SCALE_Q);
        lrow += (e0+e1)+(e2+e3);
        *(u32*)(Pw + 16) = pk4e4(e0, e1, e2, e3);
        e0 = __expf(s2[0]*SCALE_Q); e1 = __expf(s2[1]*SCALE_Q);
        e2 = __expf(s2[2]*SCALE_Q); e3 = __expf(s2[3]*SCALE_Q);
        lrow += (e0+e1)+(e2+e3);
        *(u32*)(Pw + 32) = pk4e4(e0, e1, e2, e3);
        e0 = __expf(s3[0]*SCALE_Q); e1 = __expf(s3[1]*SCALE_Q);
        e2 = __expf(s3[2]*SCALE_Q); e3 = __expf(s3[3]*SCALE_Q);
        lrow += (e0+e1)+(e2+e3);
        *(u32*)(Pw + 48) = pk4e4(e0, e1, e2, e3);
      }
    } else if (j > 0){
      // 2b. PV(window j-1): V tiles 2(j-1), 2(j-1)+1 from L2; P from dbuf
      const u8* vtA = vbase + ((size_t)(j - 1) << 16);
      const u8* vtB = vtA + 32768;
      long vA0[8], vA1[8], vB0[8], vB1[8];
      #pragma unroll
      for (int ct = 0; ct < 8; ct++){
        vA0[ct] = *(const long*)(vtA + vo0[ct]);
        vA1[ct] = *(const long*)(vtA + vo1[ct]);
        vB0[ct] = *(const long*)(vtB + vo0[ct]);
        vB1[ct] = *(const long*)(vtB + vo1[ct]);
      }
      const u8* Pp = Pb[(j - 1) & 1];
      const u8* p0 = Pp + l15*PSTR;
      const u8* p1 = Pp + (16 + l15)*PSTR;
      long pA0a = *(const long*)(p0 + q4*8);
      long pA1a = *(const long*)(p0 + 32 + q4*8);
      long pB0a = *(const long*)(p0 + 64 + q4*8);
      long pB1a = *(const long*)(p0 + 96 + q4*8);
      long pA0b = *(const long*)(p1 + q4*8);
      long pA1b = *(const long*)(p1 + 32 + q4*8);
      long pB0b = *(const long*)(p1 + 64 + q4*8);
      long pB1b = *(const long*)(p1 + 96 + q4*8);
      __builtin_amdgcn_s_setprio(1);
      #pragma unroll
      for (int ct = 0; ct < 8; ct++){
        f32x4 a0 = oacc[0][ct], a1 = oacc[1][ct];
        a0 = __builtin_amdgcn_mfma_f32_16x16x32_fp8_fp8(pA0a, vA0[ct], a0, 0, 0, 0);
        a1 = __builtin_amdgcn_mfma_f32_16x16x32_fp8_fp8(pA0b, vA0[ct], a1, 0, 0, 0);
        a0 = __builtin_amdgcn_mfma_f32_16x16x32_fp8_fp8(pA1a, vA1[ct], a0, 0, 0, 0);
        a1 = __builtin_amdgcn_mfma_f32_16x16x32_fp8_fp8(pA1b, vA1[ct], a1, 0, 0, 0);
        a0 = __builtin_amdgcn_mfma_f32_16x16x32_fp8_fp8(pB0a, vB0[ct], a0, 0, 0, 0);
        a1 = __builtin_amdgcn_mfma_f32_16x16x32_fp8_fp8(pB0b, vB0[ct], a1, 0, 0, 0);
        a0 = __builtin_amdgcn_mfma_f32_16x16x32_fp8_fp8(pB1a, vB1[ct], a0, 0, 0, 0);
        a1 = __builtin_amdgcn_mfma_f32_16x16x32_fp8_fp8(pB1b, vB1[ct], a1, 0, 0, 0);
        oacc[0][ct] = a0; oacc[1][ct] = a1;
      }
      __builtin_amdgcn_s_setprio(0);
    }
    // 4. one barrier: P(j) visible; K(j+1) DMA + V loads drained
    __syncthreads();
  }

  // ---- epilogue ----
  if (isS){
    // reduce l across q4 groups; lanes 0-15 hold row sums for (rt,kvH)
    float v = lrow;
    v += __shfl_xor(v, 16);
    v += __shfl_xor(v, 32);
    if (ln < 16) lL[kvH*32 + rt*16 + ln] = v;
  } else {
    // final PV(window 31): P(31) in Pb[1], V tiles 62,63
    const u8* vtA = vbase + ((size_t)31 << 16);
    const u8* vtB = vtA + 32768;
    long vA0[8], vA1[8], vB0[8], vB1[8];
    #pragma unroll
    for (int ct = 0; ct < 8; ct++){
      vA0[ct] = *(const long*)(vtA + vo0[ct]);
      vA1[ct] = *(const long*)(vtA + vo1[ct]);
      vB0[ct] = *(const long*)(vtB + vo0[ct]);
      vB1[ct] = *(const long*)(vtB + vo1[ct]);
    }
    const u8* Pp = Pb[1];
    const u8* p0 = Pp + l15*PSTR;
    const u8* p1 = Pp + (16 + l15)*PSTR;
    long pA0a = *(const long*)(p0 + q4*8);
    long pA1a = *(const long*)(p0 + 32 + q4*8);
    long pB0a = *(const long*)(p0 + 64 + q4*8);
    long pB1a = *(const long*)(p0 + 96 + q4*8);
    long pA0b = *(const long*)(p1 + q4*8);
    long pA1b = *(const long*)(p1 + 32 + q4*8);
    long pB0b = *(const long*)(p1 + 64 + q4*8);
    long pB1b = *(const long*)(p1 + 96 + q4*8);
    #pragma unroll
    for (int ct = 0; ct < 8; ct++){
      f32x4 a0 = oacc[0][ct], a1 = oacc[1][ct];
      a0 = __builtin_amdgcn_mfma_f32_16x16x32_fp8_fp8(pA0a, vA0[ct], a0, 0, 0, 0);
      a1 = __builtin_amdgcn_mfma_f32_16x16x32_fp8_fp8(pA0b, vA0[ct], a1, 0, 0, 0);
      a0 = __builtin_amdgcn_mfma_f32_16x16x32_fp8_fp8(pA1a, vA1[ct], a0, 0, 0, 0);
      a1 = __builtin_amdgcn_mfma_f32_16x16x32_fp8_fp8(pA1b, vA1[ct], a1, 0, 0, 0);
      a0 = __builtin_amdgcn_mfma_f32_16x16x32_fp8_fp8(pB0a, vB0[ct], a0, 0, 0, 0);
      a1 = __builtin_amdgcn_mfma_f32_16x16x32_fp8_fp8(pB0b, vB0[ct], a1, 0, 0, 0);
      a0 = __builtin_amdgcn_mfma_f32_16x16x32_fp8_fp8(pB1a, vB1[ct], a0, 0, 0, 0);
      a1 = __builtin_amdgcn_mfma_f32_16x16x32_fp8_fp8(pB1b, vB1[ct], a1, 0, 0, 0);
      oacc[0][ct] = a0; oacc[1][ct] = a1;
    }
  }
  __syncthreads();
  if (!isS){
    #pragma unroll
    for (int rr = 0; rr < 2; rr++){
      #pragma unroll
      for (int r = 0; r < 4; r++){
        int row = rr*16 + q4*4 + r;
        float inv = 1.f / (lL[row] + lL[32 + row]);
        u16* op = outO + ((size_t)b << 21) + (size_t)(q0 + row)*512 + ch0 + l15;
        #pragma unroll
        for (int ct = 0; ct < 8; ct++)
          op[ct*16] = f2b(oacc[rr][ct][r] * inv);
      }
    }
  }
}

extern "C" void kernel_launch(void* const* d_in, const int* in_sizes, int n_in,
                              void* d_out, int out_size, void* d_ws, size_t ws_size,
                              hipStream_t stream){
  const float* x     = (const float*)d_in[0];
  const float* gamma = (const float*)d_in[1];
  const float* beta  = (const float*)d_in[2];
  const float* wq_w  = (const float*)d_in[3];
  const float* wq_b  = (const float*)d_in[4];
  const float* wk_w  = (const float*)d_in[5];
  const float* wk_b  = (const float*)d_in[6];
  const float* wv_w  = (const float*)d_in[7];
  const float* wv_b  = (const float*)d_in[8];
  const float* out_w = (const float*)d_in[9];
  const float* out_b = (const float*)d_in[10];

  char* ws = (char*)d_ws;
  float* stats = (float*)ws;                                   // 1 KB
  u16* tbuf = (u16*)(ws + 4096);                               // 16 MB (t, then O)
  size_t off = 4096 + (size_t)16*1024*1024;
  u16* Wcat = (u16*)(ws + off); off += (size_t)4*512*512*2;    // 2 MB
  u8*  qb   = (u8*)(ws + off);  off += (size_t)16*1024*1024;   // Q fp8
  u8*  ktb  = (u8*)(ws + off);  off += (size_t)16*1024*1024;   // K fp8 tiled
  u8*  vtb  = (u8*)(ws + off);  off += (size_t)16*1024*1024;   // V fp8 tiled

  gn_stats<<<128, 256, 0, stream>>>(x, stats);
  gn_apply_T<<<dim3(128, 16, 4), 256, 0, stream>>>(x, stats, gamma, beta, tbuf);
  w2bf<<<1024, 256, 0, stream>>>(wq_w, wk_w, wv_w, out_w, Wcat);
  u16* Wo = Wcat + 3*512*512;
  qkv_gemm<<<dim3(128, 12), 256, 0, stream>>>(tbuf, Wcat, wq_b, wk_b, wv_b,
                                              qb, ktb, vtb);
  attn_fwd<<<dim3(128, 4), 512, 0, stream>>>(qb, ktb, vtb, tbuf);
  out_gemm<<<dim3(128, 4), 256, 0, stream>>>(tbuf, Wo, out_b, (float*)d_out, x);
}